// Round 3
// baseline (506.260 us; speedup 1.0000x reference)
//
#include <hip/hip_runtime.h>
#include <hip/hip_bf16.h>

typedef unsigned int uint;
typedef unsigned short ushort;
typedef __attribute__((ext_vector_type(8))) short short8;
typedef __attribute__((ext_vector_type(4))) float f32x4;

__device__ __forceinline__ float bf2f(ushort u) {
    union { uint i; float f; } v; v.i = ((uint)u) << 16; return v.f;
}
__device__ __forceinline__ ushort f2bf(float f) {
    union { float f; uint i; } v; v.f = f;
    uint x = v.i;
    uint r = (x + 0x7FFFu + ((x >> 16) & 1u)) >> 16;
    return (ushort)r;
}

// ---------------- graph prep ----------------

__global__ void k_degree(const int* __restrict__ dst, int* __restrict__ deg, int e) {
    int i = blockIdx.x * 256 + threadIdx.x;
    if (i < e) atomicAdd(&deg[dst[i]], 1);
}

__global__ void k_dinv(const int* __restrict__ deg, float* __restrict__ dinv, int n) {
    int i = blockIdx.x * 256 + threadIdx.x;
    if (i < n) dinv[i] = rsqrtf((float)deg[i] + 1.0f);  // +1 self-loop
}

// 3-kernel exclusive scan of edge-degree -> offsets. chunk = 1024/block.
__global__ void k_scan_a(const int* __restrict__ deg, int* __restrict__ bsum, int n) {
    __shared__ int sd[256];
    int t = threadIdx.x;
    int base = blockIdx.x * 1024 + t * 4;
    int s = 0;
#pragma unroll
    for (int j = 0; j < 4; ++j) { int idx = base + j; if (idx < n) s += deg[idx]; }
    sd[t] = s; __syncthreads();
    for (int off = 1; off < 256; off <<= 1) {
        int v = (t >= off) ? sd[t - off] : 0;
        __syncthreads();
        sd[t] += v;
        __syncthreads();
    }
    if (t == 255) bsum[blockIdx.x] = sd[255];
}

__global__ void k_scan_b(const int* __restrict__ bsum, int* __restrict__ boff, int nb) {
    __shared__ int sd[256];
    int t = threadIdx.x;
    int v0 = (t < nb) ? bsum[t] : 0;
    sd[t] = v0; __syncthreads();
    for (int off = 1; off < 256; off <<= 1) {
        int v = (t >= off) ? sd[t - off] : 0;
        __syncthreads();
        sd[t] += v;
        __syncthreads();
    }
    if (t < nb) boff[t] = sd[t] - v0;  // exclusive
}

__global__ void k_scan_c(const int* __restrict__ deg, const int* __restrict__ boff,
                         int* __restrict__ offs, int n) {
    __shared__ int sd[256];
    int t = threadIdx.x;
    int base = blockIdx.x * 1024 + t * 4;
    int vals[4]; int s = 0;
#pragma unroll
    for (int j = 0; j < 4; ++j) {
        int idx = base + j;
        vals[j] = (idx < n) ? deg[idx] : 0;
        s += vals[j];
    }
    sd[t] = s; __syncthreads();
    for (int off = 1; off < 256; off <<= 1) {
        int v = (t >= off) ? sd[t - off] : 0;
        __syncthreads();
        sd[t] += v;
        __syncthreads();
    }
    int run = boff[blockIdx.x] + (sd[t] - s);
#pragma unroll
    for (int j = 0; j < 4; ++j) {
        int idx = base + j;
        if (idx < n) { offs[idx] = run; run += vals[j]; }
    }
}

__global__ void k_fill(const int* __restrict__ src, const int* __restrict__ dst,
                       const int* __restrict__ offs, int* __restrict__ cursor,
                       int* __restrict__ csr, int e) {
    int i = blockIdx.x * 256 + threadIdx.x;
    if (i < e) {
        int d = dst[i];
        int p = offs[d] + atomicAdd(&cursor[d], 1);
        csr[p] = src[i];
    }
}

// ---------------- GEMM1: h1s = (x@W1)*dinv (bf16), xfc = relu(x@We+be) (bf16) ----------------

__global__ __launch_bounds__(512) void k_gemm1(
    const float* __restrict__ x, const float* __restrict__ W1, const float* __restrict__ We,
    const float* __restrict__ be, const float* __restrict__ dinv,
    ushort* __restrict__ h1s, ushort* __restrict__ xfc, int n)
{
    __shared__ __align__(16) ushort Bt[256][72];  // [col][k_local], pad 72 for banks
    int tid = threadIdx.x;
    int w = tid >> 6, lane = tid & 63;
    int ln15 = lane & 15, g = lane >> 4;
    int rowBase = blockIdx.x * 128 + w * 16;
    int r = rowBase + ln15;
    bool valid = r < n;

    short8 a[4];
#pragma unroll
    for (int ks = 0; ks < 4; ++ks) {
        float4 f0 = make_float4(0.f, 0.f, 0.f, 0.f), f1 = f0;
        if (valid) {
            const float* p = x + (size_t)r * 128 + ks * 32 + g * 8;
            f0 = *reinterpret_cast<const float4*>(p);
            f1 = *reinterpret_cast<const float4*>(p + 4);
        }
        short8 v;
        v[0] = (short)f2bf(f0.x); v[1] = (short)f2bf(f0.y);
        v[2] = (short)f2bf(f0.z); v[3] = (short)f2bf(f0.w);
        v[4] = (short)f2bf(f1.x); v[5] = (short)f2bf(f1.y);
        v[6] = (short)f2bf(f1.z); v[7] = (short)f2bf(f1.w);
        a[ks] = v;
    }

    f32x4 acc[16];
#pragma unroll
    for (int i = 0; i < 16; ++i) acc[i] = (f32x4){0.f, 0.f, 0.f, 0.f};

    for (int s = 0; s < 2; ++s) {
        for (int i = tid; i < 8192; i += 512) {
            int kl = i >> 7, j = i & 127;
            int kg = s * 64 + kl;
            Bt[j][kl]       = f2bf(W1[kg * 128 + j]);
            Bt[128 + j][kl] = f2bf(We[kg * 128 + j]);
        }
        __syncthreads();
#pragma unroll
        for (int t2 = 0; t2 < 2; ++t2) {
            short8 af = a[s * 2 + t2];
#pragma unroll
            for (int jf = 0; jf < 16; ++jf) {
                short8 bf = *reinterpret_cast<const short8*>(&Bt[jf * 16 + ln15][t2 * 32 + g * 8]);
                acc[jf] = __builtin_amdgcn_mfma_f32_16x16x32_bf16(af, bf, acc[jf], 0, 0, 0);
            }
        }
        __syncthreads();
    }

    float dv[4];
#pragma unroll
    for (int q = 0; q < 4; ++q) {
        int rr = rowBase + g * 4 + q;
        dv[q] = (rr < n) ? dinv[rr] : 0.f;
    }

    // D layout: col = lane&15, row = (lane>>4)*4 + q
#pragma unroll
    for (int jf = 0; jf < 16; ++jf) {
        int col = jf * 16 + ln15;
#pragma unroll
        for (int q = 0; q < 4; ++q) {
            int rr = rowBase + g * 4 + q;
            if (rr < n) {
                float v = acc[jf][q];
                if (col < 128) {
                    h1s[(size_t)rr * 128 + col] = f2bf(v * dv[q]);
                } else {
                    float vv = fmaxf(v + be[col - 128], 0.f);
                    xfc[(size_t)rr * 128 + (col - 128)] = f2bf(vv);
                }
            }
        }
    }
}

// ---------------- GEMM2: h2s = (h@W2)*dinv (bf16 in, bf16 out) ----------------

__global__ __launch_bounds__(512) void k_gemm2(
    const ushort* __restrict__ h, const float* __restrict__ W2, const float* __restrict__ dinv,
    ushort* __restrict__ h2s, int n)
{
    __shared__ __align__(16) ushort Bt[128][72];
    int tid = threadIdx.x;
    int w = tid >> 6, lane = tid & 63;
    int ln15 = lane & 15, g = lane >> 4;
    int rowBase = blockIdx.x * 128 + w * 16;
    int r = rowBase + ln15;
    bool valid = r < n;

    short8 a[4];
#pragma unroll
    for (int ks = 0; ks < 4; ++ks) {
        short8 v = (short8){0,0,0,0,0,0,0,0};
        if (valid) v = *reinterpret_cast<const short8*>(h + (size_t)r * 128 + ks * 32 + g * 8);
        a[ks] = v;
    }

    f32x4 acc[8];
#pragma unroll
    for (int i = 0; i < 8; ++i) acc[i] = (f32x4){0.f, 0.f, 0.f, 0.f};

    for (int s = 0; s < 2; ++s) {
        for (int i = tid; i < 8192; i += 512) {
            int kl = i >> 7, j = i & 127;
            Bt[j][kl] = f2bf(W2[(s * 64 + kl) * 128 + j]);
        }
        __syncthreads();
#pragma unroll
        for (int t2 = 0; t2 < 2; ++t2) {
            short8 af = a[s * 2 + t2];
#pragma unroll
            for (int jf = 0; jf < 8; ++jf) {
                short8 bf = *reinterpret_cast<const short8*>(&Bt[jf * 16 + ln15][t2 * 32 + g * 8]);
                acc[jf] = __builtin_amdgcn_mfma_f32_16x16x32_bf16(af, bf, acc[jf], 0, 0, 0);
            }
        }
        __syncthreads();
    }

    float dv[4];
#pragma unroll
    for (int q = 0; q < 4; ++q) {
        int rr = rowBase + g * 4 + q;
        dv[q] = (rr < n) ? dinv[rr] : 0.f;
    }

#pragma unroll
    for (int jf = 0; jf < 8; ++jf) {
        int col = jf * 16 + ln15;
#pragma unroll
        for (int q = 0; q < 4; ++q) {
            int rr = rowBase + g * 4 + q;
            if (rr < n) h2s[(size_t)rr * 128 + col] = f2bf(acc[jf][q] * dv[q]);
        }
    }
}

// ---------------- aggregation 1 ----------------
// h_i = relu(dinv_i*(sum_{s in N(i)} h1s[s] + h1s[i]) + b1) + xfc_i
// 16-lane group per node; lane owns 8 channels (16B gathers). Edge loop
// unrolled x8; invalid edges clamp to zero-row index n. csr padded by 8.

__global__ __launch_bounds__(256) void k_agg1(
    const int* __restrict__ csr, const int* __restrict__ offs, const int* __restrict__ degE,
    const float* __restrict__ dinv, const ushort* __restrict__ h1s, const ushort* __restrict__ xfc,
    const float* __restrict__ b1, ushort* __restrict__ h, int n)
{
    int t = threadIdx.x;
    int g = t >> 4, li = t & 15;
    int node = blockIdx.x * 16 + g;
    if (node >= n) return;
    int off = offs[node], cnt = degE[node];
    float di = dinv[node];
    int c0 = li * 8;
    float acc[8];
#pragma unroll
    for (int e = 0; e < 8; ++e) acc[e] = 0.f;

    for (int base = 0; base < cnt; base += 8) {
        int idx[8];
#pragma unroll
        for (int q = 0; q < 8; ++q) {
            int s = csr[off + base + q];       // group-uniform, L1 broadcast
            idx[q] = (base + q < cnt) ? s : n; // zero row for tail
        }
        uint4 u[8];
#pragma unroll
        for (int q = 0; q < 8; ++q)
            u[q] = *reinterpret_cast<const uint4*>(h1s + (size_t)idx[q] * 128 + c0);
#pragma unroll
        for (int q = 0; q < 8; ++q) {
            const uint* uw = reinterpret_cast<const uint*>(&u[q]);
#pragma unroll
            for (int p = 0; p < 4; ++p) {
                acc[2 * p]     += bf2f((ushort)(uw[p] & 0xffff));
                acc[2 * p + 1] += bf2f((ushort)(uw[p] >> 16));
            }
        }
    }

    uint4 us = *reinterpret_cast<const uint4*>(h1s + (size_t)node * 128 + c0);
    uint4 ux = *reinterpret_cast<const uint4*>(xfc + (size_t)node * 128 + c0);
    float4 bA = *reinterpret_cast<const float4*>(b1 + c0);
    float4 bB = *reinterpret_cast<const float4*>(b1 + c0 + 4);
    float bb[8] = {bA.x, bA.y, bA.z, bA.w, bB.x, bB.y, bB.z, bB.w};
    const uint* usw = reinterpret_cast<const uint*>(&us);
    const uint* uxw = reinterpret_cast<const uint*>(&ux);
    uint outw[4];
#pragma unroll
    for (int p = 0; p < 4; ++p) {
        float s0 = bf2f((ushort)(usw[p] & 0xffff));
        float s1 = bf2f((ushort)(usw[p] >> 16));
        float v0 = fmaxf((acc[2 * p] + s0) * di + bb[2 * p], 0.f)
                 + bf2f((ushort)(uxw[p] & 0xffff));
        float v1 = fmaxf((acc[2 * p + 1] + s1) * di + bb[2 * p + 1], 0.f)
                 + bf2f((ushort)(uxw[p] >> 16));
        outw[p] = (uint)f2bf(v0) | ((uint)f2bf(v1) << 16);
    }
    *reinterpret_cast<uint4*>(h + (size_t)node * 128 + c0) =
        make_uint4(outw[0], outw[1], outw[2], outw[3]);
}

// ---------------- aggregation 2 + residual + pool (no per-node output) ----------------
// pool_c += relu(dinv_i*(sum h2s[s] + h2s[i]) + b2)_c + h_i_c

__global__ __launch_bounds__(256) void k_agg2(
    const int* __restrict__ csr, const int* __restrict__ offs, const int* __restrict__ degE,
    const float* __restrict__ dinv, const ushort* __restrict__ h2s, const ushort* __restrict__ hres,
    const float* __restrict__ b2, float* __restrict__ pooled, int n)
{
    __shared__ float lpool[128];
    int t = threadIdx.x;
    if (t < 128) lpool[t] = 0.f;
    __syncthreads();
    int g = t >> 4, li = t & 15;
    int node = blockIdx.x * 16 + g;
    bool valid = node < n;
    int nodeC = valid ? node : (n - 1);
    int off = offs[nodeC];
    int cnt = valid ? degE[nodeC] : 0;
    float di = dinv[nodeC];
    int c0 = li * 8;
    float acc[8];
#pragma unroll
    for (int e = 0; e < 8; ++e) acc[e] = 0.f;

    for (int base = 0; base < cnt; base += 8) {
        int idx[8];
#pragma unroll
        for (int q = 0; q < 8; ++q) {
            int s = csr[off + base + q];
            idx[q] = (base + q < cnt) ? s : n;
        }
        uint4 u[8];
#pragma unroll
        for (int q = 0; q < 8; ++q)
            u[q] = *reinterpret_cast<const uint4*>(h2s + (size_t)idx[q] * 128 + c0);
#pragma unroll
        for (int q = 0; q < 8; ++q) {
            const uint* uw = reinterpret_cast<const uint*>(&u[q]);
#pragma unroll
            for (int p = 0; p < 4; ++p) {
                acc[2 * p]     += bf2f((ushort)(uw[p] & 0xffff));
                acc[2 * p + 1] += bf2f((ushort)(uw[p] >> 16));
            }
        }
    }

    uint4 us = *reinterpret_cast<const uint4*>(h2s + (size_t)nodeC * 128 + c0);
    uint4 ur = *reinterpret_cast<const uint4*>(hres + (size_t)nodeC * 128 + c0);
    float4 bA = *reinterpret_cast<const float4*>(b2 + c0);
    float4 bB = *reinterpret_cast<const float4*>(b2 + c0 + 4);
    float bb[8] = {bA.x, bA.y, bA.z, bA.w, bB.x, bB.y, bB.z, bB.w};
    const uint* usw = reinterpret_cast<const uint*>(&us);
    const uint* urw = reinterpret_cast<const uint*>(&ur);
    float pv[8];
#pragma unroll
    for (int p = 0; p < 4; ++p) {
        float s0 = bf2f((ushort)(usw[p] & 0xffff));
        float s1 = bf2f((ushort)(usw[p] >> 16));
        float v0 = fmaxf((acc[2 * p] + s0) * di + bb[2 * p], 0.f)
                 + bf2f((ushort)(urw[p] & 0xffff));
        float v1 = fmaxf((acc[2 * p + 1] + s1) * di + bb[2 * p + 1], 0.f)
                 + bf2f((ushort)(urw[p] >> 16));
        pv[2 * p]     = valid ? v0 : 0.f;
        pv[2 * p + 1] = valid ? v1 : 0.f;
    }
    // reduce across the 4 groups of this wave: lanes with same (t&15) share channels
#pragma unroll
    for (int e = 0; e < 8; ++e) {
        pv[e] += __shfl_xor(pv[e], 16);
        pv[e] += __shfl_xor(pv[e], 32);
    }
    if ((t & 63) < 16) {
#pragma unroll
        for (int e = 0; e < 8; ++e) atomicAdd(&lpool[c0 + e], pv[e]);
    }
    __syncthreads();
    if (t < 128) atomicAdd(&pooled[t], lpool[t]);
}

// ---------------- final: sigmoid(mean @ Wfc + bfc) ----------------

__global__ void k_final(const float* __restrict__ pooled, const float* __restrict__ Wfc,
                        const float* __restrict__ bfc, float* __restrict__ out, float invN) {
    int lane = threadIdx.x;
    float s = pooled[2 * lane] * invN * Wfc[2 * lane] +
              pooled[2 * lane + 1] * invN * Wfc[2 * lane + 1];
#pragma unroll
    for (int off = 32; off > 0; off >>= 1) s += __shfl_down(s, off);
    if (lane == 0) out[0] = 1.f / (1.f + expf(-(s + bfc[0])));
}

// ---------------- launch ----------------

extern "C" void kernel_launch(void* const* d_in, const int* in_sizes, int n_in,
                              void* d_out, int out_size, void* d_ws, size_t ws_size,
                              hipStream_t stream) {
    const float* x   = (const float*)d_in[0];
    const int*   ei  = (const int*)d_in[1];
    const float* W1  = (const float*)d_in[2];
    const float* b1  = (const float*)d_in[3];
    const float* W2  = (const float*)d_in[4];
    const float* b2  = (const float*)d_in[5];
    const float* We  = (const float*)d_in[6];
    const float* be  = (const float*)d_in[7];
    const float* Wfc = (const float*)d_in[8];
    const float* bfc = (const float*)d_in[9];
    float* out = (float*)d_out;

    const int N = in_sizes[0] / 128;
    const int E = in_sizes[1] / 2;
    const int* src = ei;
    const int* dst = ei + E;

    char* w = (char*)d_ws;
    size_t off = 0;
    auto take = [&](size_t bytes) -> void* {
        void* p = w + off;
        off = (off + bytes + 255) & ~(size_t)255;
        return p;
    };
    int*    deg    = (int*)take((size_t)N * 4);
    int*    offs   = (int*)take((size_t)N * 4);
    int*    cursor = (int*)take((size_t)N * 4);
    float*  dinv   = (float*)take((size_t)N * 4);
    int*    bsum   = (int*)take(1024);
    int*    boff   = (int*)take(1024);
    int*    csr    = (int*)take((size_t)(E + 8) * 4);
    ushort* h1s    = (ushort*)take((size_t)(N + 1) * 128 * 2);  // row N = zeros
    ushort* xfc    = (ushort*)take((size_t)N * 128 * 2);
    ushort* h      = (ushort*)take((size_t)N * 128 * 2);
    ushort* h2s    = (ushort*)take((size_t)(N + 1) * 128 * 2);  // row N = zeros
    float*  pooled = (float*)take(512);

    const int nbE = (E + 255) / 256;
    const int nbScan = (N + 1023) / 1024;

    hipMemsetAsync(deg, 0, (size_t)N * 4, stream);
    hipMemsetAsync(cursor, 0, (size_t)N * 4, stream);
    hipMemsetAsync(pooled, 0, 512, stream);
    hipMemsetAsync(h1s + (size_t)N * 128, 0, 256, stream);
    hipMemsetAsync(h2s + (size_t)N * 128, 0, 256, stream);

    k_degree<<<nbE, 256, 0, stream>>>(dst, deg, E);
    k_dinv<<<(N + 255) / 256, 256, 0, stream>>>(deg, dinv, N);
    k_scan_a<<<nbScan, 256, 0, stream>>>(deg, bsum, N);
    k_scan_b<<<1, 256, 0, stream>>>(bsum, boff, nbScan);
    k_scan_c<<<nbScan, 256, 0, stream>>>(deg, boff, offs, N);
    k_fill<<<nbE, 256, 0, stream>>>(src, dst, offs, cursor, csr, E);

    k_gemm1<<<(N + 127) / 128, 512, 0, stream>>>(x, W1, We, be, dinv, h1s, xfc, N);
    k_agg1<<<(N + 15) / 16, 256, 0, stream>>>(csr, offs, deg, dinv, h1s, xfc, b1, h, N);
    k_gemm2<<<(N + 127) / 128, 512, 0, stream>>>(h, W2, dinv, h2s, N);
    k_agg2<<<(N + 15) / 16, 256, 0, stream>>>(csr, offs, deg, dinv, h2s, h, b2, pooled, N);
    k_final<<<1, 64, 0, stream>>>(pooled, Wfc, bfc, out, 1.0f / (float)N);
}

// Round 5
// 441.879 us; speedup vs baseline: 1.1457x; 1.1457x over previous
//
#include <hip/hip_runtime.h>
#include <hip/hip_bf16.h>

typedef unsigned int uint;
typedef unsigned short ushort;
typedef unsigned char uchar;
typedef __attribute__((ext_vector_type(8))) short short8;
typedef __attribute__((ext_vector_type(4))) float f32x4;

__device__ __forceinline__ float bf2f(ushort u) {
    union { uint i; float f; } v; v.i = ((uint)u) << 16; return v.f;
}
__device__ __forceinline__ ushort f2bf(float f) {
    union { float f; uint i; } v; v.f = f;
    uint x = v.i;
    uint r = (x + 0x7FFFu + ((x >> 16) & 1u)) >> 16;
    return (ushort)r;
}
// fp8 e4m3 encode via HW cvt
__device__ __forceinline__ uchar f2q(float f) {
    return (uchar)(__builtin_amdgcn_cvt_pk_fp8_f32(f, 0.f, 0, false) & 0xFF);
}
// decode 4 fp8 from a word (literal selectors required)
__device__ __forceinline__ void q2f4(uint w, float* o) {
    o[0] = __builtin_amdgcn_cvt_f32_fp8(w, 0);
    o[1] = __builtin_amdgcn_cvt_f32_fp8(w, 1);
    o[2] = __builtin_amdgcn_cvt_f32_fp8(w, 2);
    o[3] = __builtin_amdgcn_cvt_f32_fp8(w, 3);
}

// ---------------- graph prep ----------------

__global__ void k_degree(const int* __restrict__ dst, int* __restrict__ deg, int e) {
    int i = blockIdx.x * 256 + threadIdx.x;
    if (i < e) atomicAdd(&deg[dst[i]], 1);
}

__global__ void k_dinv(const int* __restrict__ deg, float* __restrict__ dinv, int n) {
    int i = blockIdx.x * 256 + threadIdx.x;
    if (i < n) dinv[i] = rsqrtf((float)deg[i] + 1.0f);  // +1 self-loop
}

// 3-kernel exclusive scan of edge-degree -> offsets. chunk = 1024/block.
__global__ void k_scan_a(const int* __restrict__ deg, int* __restrict__ bsum, int n) {
    __shared__ int sd[256];
    int t = threadIdx.x;
    int base = blockIdx.x * 1024 + t * 4;
    int s = 0;
#pragma unroll
    for (int j = 0; j < 4; ++j) { int idx = base + j; if (idx < n) s += deg[idx]; }
    sd[t] = s; __syncthreads();
    for (int off = 1; off < 256; off <<= 1) {
        int v = (t >= off) ? sd[t - off] : 0;
        __syncthreads();
        sd[t] += v;
        __syncthreads();
    }
    if (t == 255) bsum[blockIdx.x] = sd[255];
}

__global__ void k_scan_b(const int* __restrict__ bsum, int* __restrict__ boff, int nb) {
    __shared__ int sd[256];
    int t = threadIdx.x;
    int v0 = (t < nb) ? bsum[t] : 0;
    sd[t] = v0; __syncthreads();
    for (int off = 1; off < 256; off <<= 1) {
        int v = (t >= off) ? sd[t - off] : 0;
        __syncthreads();
        sd[t] += v;
        __syncthreads();
    }
    if (t < nb) boff[t] = sd[t] - v0;  // exclusive
}

__global__ void k_scan_c(const int* __restrict__ deg, const int* __restrict__ boff,
                         int* __restrict__ offs, int n) {
    __shared__ int sd[256];
    int t = threadIdx.x;
    int base = blockIdx.x * 1024 + t * 4;
    int vals[4]; int s = 0;
#pragma unroll
    for (int j = 0; j < 4; ++j) {
        int idx = base + j;
        vals[j] = (idx < n) ? deg[idx] : 0;
        s += vals[j];
    }
    sd[t] = s; __syncthreads();
    for (int off = 1; off < 256; off <<= 1) {
        int v = (t >= off) ? sd[t - off] : 0;
        __syncthreads();
        sd[t] += v;
        __syncthreads();
    }
    int run = boff[blockIdx.x] + (sd[t] - s);
#pragma unroll
    for (int j = 0; j < 4; ++j) {
        int idx = base + j;
        if (idx < n) { offs[idx] = run; run += vals[j]; }
    }
}

__global__ void k_fill(const int* __restrict__ src, const int* __restrict__ dst,
                       const int* __restrict__ offs, int* __restrict__ cursor,
                       int* __restrict__ csr, int e) {
    int i = blockIdx.x * 256 + threadIdx.x;
    if (i < e) {
        int d = dst[i];
        int p = offs[d] + atomicAdd(&cursor[d], 1);
        csr[p] = src[i];
    }
}

// ---------------- GEMM1: h1q = fp8((x@W1)*dinv), xfc = bf16(relu(x@We+be)) ----------------

__global__ __launch_bounds__(512) void k_gemm1(
    const float* __restrict__ x, const float* __restrict__ W1, const float* __restrict__ We,
    const float* __restrict__ be, const float* __restrict__ dinv,
    uchar* __restrict__ h1q, ushort* __restrict__ xfc, int n)
{
    __shared__ __align__(16) ushort Bt[256][72];  // [col][k_local], pad 72 for banks
    int tid = threadIdx.x;
    int w = tid >> 6, lane = tid & 63;
    int ln15 = lane & 15, g = lane >> 4;
    int rowBase = blockIdx.x * 128 + w * 16;
    int r = rowBase + ln15;
    bool valid = r < n;

    short8 a[4];
#pragma unroll
    for (int ks = 0; ks < 4; ++ks) {
        float4 f0 = make_float4(0.f, 0.f, 0.f, 0.f), f1 = f0;
        if (valid) {
            const float* p = x + (size_t)r * 128 + ks * 32 + g * 8;
            f0 = *reinterpret_cast<const float4*>(p);
            f1 = *reinterpret_cast<const float4*>(p + 4);
        }
        short8 v;
        v[0] = (short)f2bf(f0.x); v[1] = (short)f2bf(f0.y);
        v[2] = (short)f2bf(f0.z); v[3] = (short)f2bf(f0.w);
        v[4] = (short)f2bf(f1.x); v[5] = (short)f2bf(f1.y);
        v[6] = (short)f2bf(f1.z); v[7] = (short)f2bf(f1.w);
        a[ks] = v;
    }

    f32x4 acc[16];
#pragma unroll
    for (int i = 0; i < 16; ++i) acc[i] = (f32x4){0.f, 0.f, 0.f, 0.f};

    for (int s = 0; s < 2; ++s) {
        for (int i = tid; i < 8192; i += 512) {
            int kl = i >> 7, j = i & 127;
            int kg = s * 64 + kl;
            Bt[j][kl]       = f2bf(W1[kg * 128 + j]);
            Bt[128 + j][kl] = f2bf(We[kg * 128 + j]);
        }
        __syncthreads();
#pragma unroll
        for (int t2 = 0; t2 < 2; ++t2) {
            short8 af = a[s * 2 + t2];
#pragma unroll
            for (int jf = 0; jf < 16; ++jf) {
                short8 bf = *reinterpret_cast<const short8*>(&Bt[jf * 16 + ln15][t2 * 32 + g * 8]);
                acc[jf] = __builtin_amdgcn_mfma_f32_16x16x32_bf16(af, bf, acc[jf], 0, 0, 0);
            }
        }
        __syncthreads();
    }

    float dv[4];
#pragma unroll
    for (int q = 0; q < 4; ++q) {
        int rr = rowBase + g * 4 + q;
        dv[q] = (rr < n) ? dinv[rr] : 0.f;
    }

    // D layout: col = lane&15, row = (lane>>4)*4 + q
#pragma unroll
    for (int jf = 0; jf < 16; ++jf) {
        int col = jf * 16 + ln15;
#pragma unroll
        for (int q = 0; q < 4; ++q) {
            int rr = rowBase + g * 4 + q;
            if (rr < n) {
                float v = acc[jf][q];
                if (col < 128) {
                    h1q[(size_t)rr * 128 + col] = f2q(v * dv[q]);
                } else {
                    float vv = fmaxf(v + be[col - 128], 0.f);
                    xfc[(size_t)rr * 128 + (col - 128)] = f2bf(vv);
                }
            }
        }
    }
}

// ---------------- GEMM2: h2q = fp8((h@W2)*dinv) (bf16 in) ----------------

__global__ __launch_bounds__(512) void k_gemm2(
    const ushort* __restrict__ h, const float* __restrict__ W2, const float* __restrict__ dinv,
    uchar* __restrict__ h2q, int n)
{
    __shared__ __align__(16) ushort Bt[128][72];
    int tid = threadIdx.x;
    int w = tid >> 6, lane = tid & 63;
    int ln15 = lane & 15, g = lane >> 4;
    int rowBase = blockIdx.x * 128 + w * 16;
    int r = rowBase + ln15;
    bool valid = r < n;

    short8 a[4];
#pragma unroll
    for (int ks = 0; ks < 4; ++ks) {
        short8 v = (short8){0,0,0,0,0,0,0,0};
        if (valid) v = *reinterpret_cast<const short8*>(h + (size_t)r * 128 + ks * 32 + g * 8);
        a[ks] = v;
    }

    f32x4 acc[8];
#pragma unroll
    for (int i = 0; i < 8; ++i) acc[i] = (f32x4){0.f, 0.f, 0.f, 0.f};

    for (int s = 0; s < 2; ++s) {
        for (int i = tid; i < 8192; i += 512) {
            int kl = i >> 7, j = i & 127;
            Bt[j][kl] = f2bf(W2[(s * 64 + kl) * 128 + j]);
        }
        __syncthreads();
#pragma unroll
        for (int t2 = 0; t2 < 2; ++t2) {
            short8 af = a[s * 2 + t2];
#pragma unroll
            for (int jf = 0; jf < 8; ++jf) {
                short8 bf = *reinterpret_cast<const short8*>(&Bt[jf * 16 + ln15][t2 * 32 + g * 8]);
                acc[jf] = __builtin_amdgcn_mfma_f32_16x16x32_bf16(af, bf, acc[jf], 0, 0, 0);
            }
        }
        __syncthreads();
    }

    float dv[4];
#pragma unroll
    for (int q = 0; q < 4; ++q) {
        int rr = rowBase + g * 4 + q;
        dv[q] = (rr < n) ? dinv[rr] : 0.f;
    }

#pragma unroll
    for (int jf = 0; jf < 8; ++jf) {
        int col = jf * 16 + ln15;
#pragma unroll
        for (int q = 0; q < 4; ++q) {
            int rr = rowBase + g * 4 + q;
            if (rr < n) h2q[(size_t)rr * 128 + col] = f2q(acc[jf][q] * dv[q]);
        }
    }
}

// ---------------- aggregation 1 ----------------
// h_i = relu(dinv_i*(sum_{s in N(i)} h1q[s] + h1q[i]) + b1) + xfc_i   (bf16 out)
// 8-lane group per node; lane owns 16 channels (16B fp8 gathers). Edge loop
// unrolled x8; tail edges clamp to zero-row n. csr padded by 8.

__global__ __launch_bounds__(256) void k_agg1(
    const int* __restrict__ csr, const int* __restrict__ offs, const int* __restrict__ degE,
    const float* __restrict__ dinv, const uchar* __restrict__ h1q, const ushort* __restrict__ xfc,
    const float* __restrict__ b1, ushort* __restrict__ h, int n)
{
    int t = threadIdx.x;
    int g = t >> 3, li = t & 7;
    int node = blockIdx.x * 32 + g;
    if (node >= n) return;
    int off = offs[node], cnt = degE[node];
    float di = dinv[node];
    int c0 = li * 16;
    float acc[16];
#pragma unroll
    for (int e = 0; e < 16; ++e) acc[e] = 0.f;

    for (int base = 0; base < cnt; base += 8) {
        int idx[8];
#pragma unroll
        for (int q = 0; q < 8; ++q) {
            int s = csr[off + base + q];       // group-uniform
            idx[q] = (base + q < cnt) ? s : n; // zero row for tail
        }
        uint4 u[8];
#pragma unroll
        for (int q = 0; q < 8; ++q)
            u[q] = *reinterpret_cast<const uint4*>(h1q + (size_t)idx[q] * 128 + c0);
#pragma unroll
        for (int q = 0; q < 8; ++q) {
            const uint* uw = reinterpret_cast<const uint*>(&u[q]);
#pragma unroll
            for (int p = 0; p < 4; ++p) {
                float d4[4]; q2f4(uw[p], d4);
                acc[4 * p + 0] += d4[0];
                acc[4 * p + 1] += d4[1];
                acc[4 * p + 2] += d4[2];
                acc[4 * p + 3] += d4[3];
            }
        }
    }

    uint4 us = *reinterpret_cast<const uint4*>(h1q + (size_t)node * 128 + c0);
    const uint* usw = reinterpret_cast<const uint*>(&us);
    float sdec[16];
#pragma unroll
    for (int p = 0; p < 4; ++p) q2f4(usw[p], &sdec[4 * p]);
    uint4 ux0 = *reinterpret_cast<const uint4*>(xfc + (size_t)node * 128 + c0);
    uint4 ux1 = *reinterpret_cast<const uint4*>(xfc + (size_t)node * 128 + c0 + 8);
    uint uxw[8] = {ux0.x, ux0.y, ux0.z, ux0.w, ux1.x, ux1.y, ux1.z, ux1.w};
    float bb[16];
#pragma unroll
    for (int p = 0; p < 4; ++p) {
        float4 bq = *reinterpret_cast<const float4*>(b1 + c0 + p * 4);
        bb[4 * p] = bq.x; bb[4 * p + 1] = bq.y; bb[4 * p + 2] = bq.z; bb[4 * p + 3] = bq.w;
    }
    uint outw[8];
#pragma unroll
    for (int j = 0; j < 8; ++j) {
        int e0 = 2 * j, e1 = 2 * j + 1;
        float v0 = fmaxf((acc[e0] + sdec[e0]) * di + bb[e0], 0.f) + bf2f((ushort)(uxw[j] & 0xffff));
        float v1 = fmaxf((acc[e1] + sdec[e1]) * di + bb[e1], 0.f) + bf2f((ushort)(uxw[j] >> 16));
        outw[j] = (uint)f2bf(v0) | ((uint)f2bf(v1) << 16);
    }
    ushort* hp = h + (size_t)node * 128 + c0;
    *reinterpret_cast<uint4*>(hp)     = make_uint4(outw[0], outw[1], outw[2], outw[3]);
    *reinterpret_cast<uint4*>(hp + 8) = make_uint4(outw[4], outw[5], outw[6], outw[7]);
}

// ---------------- aggregation 2 + residual + pool (no per-node output) ----------------
// pool_c += relu(dinv_i*(sum h2q[s] + h2q[i]) + b2)_c + h_i_c

__global__ __launch_bounds__(256) void k_agg2(
    const int* __restrict__ csr, const int* __restrict__ offs, const int* __restrict__ degE,
    const float* __restrict__ dinv, const uchar* __restrict__ h2q, const ushort* __restrict__ hres,
    const float* __restrict__ b2, float* __restrict__ pooled, int n)
{
    __shared__ float lpool[128];
    int t = threadIdx.x;
    if (t < 128) lpool[t] = 0.f;
    __syncthreads();
    int g = t >> 3, li = t & 7;
    int node = blockIdx.x * 32 + g;
    bool valid = node < n;
    int nodeC = valid ? node : (n - 1);
    int off = offs[nodeC];
    int cnt = valid ? degE[nodeC] : 0;
    float di = dinv[nodeC];
    int c0 = li * 16;
    float acc[16];
#pragma unroll
    for (int e = 0; e < 16; ++e) acc[e] = 0.f;

    for (int base = 0; base < cnt; base += 8) {
        int idx[8];
#pragma unroll
        for (int q = 0; q < 8; ++q) {
            int s = csr[off + base + q];
            idx[q] = (base + q < cnt) ? s : n;
        }
        uint4 u[8];
#pragma unroll
        for (int q = 0; q < 8; ++q)
            u[q] = *reinterpret_cast<const uint4*>(h2q + (size_t)idx[q] * 128 + c0);
#pragma unroll
        for (int q = 0; q < 8; ++q) {
            const uint* uw = reinterpret_cast<const uint*>(&u[q]);
#pragma unroll
            for (int p = 0; p < 4; ++p) {
                float d4[4]; q2f4(uw[p], d4);
                acc[4 * p + 0] += d4[0];
                acc[4 * p + 1] += d4[1];
                acc[4 * p + 2] += d4[2];
                acc[4 * p + 3] += d4[3];
            }
        }
    }

    uint4 us = *reinterpret_cast<const uint4*>(h2q + (size_t)nodeC * 128 + c0);
    const uint* usw = reinterpret_cast<const uint*>(&us);
    float sdec[16];
#pragma unroll
    for (int p = 0; p < 4; ++p) q2f4(usw[p], &sdec[4 * p]);
    uint4 ur0 = *reinterpret_cast<const uint4*>(hres + (size_t)nodeC * 128 + c0);
    uint4 ur1 = *reinterpret_cast<const uint4*>(hres + (size_t)nodeC * 128 + c0 + 8);
    uint urw[8] = {ur0.x, ur0.y, ur0.z, ur0.w, ur1.x, ur1.y, ur1.z, ur1.w};
    float bb[16];
#pragma unroll
    for (int p = 0; p < 4; ++p) {
        float4 bq = *reinterpret_cast<const float4*>(b2 + c0 + p * 4);
        bb[4 * p] = bq.x; bb[4 * p + 1] = bq.y; bb[4 * p + 2] = bq.z; bb[4 * p + 3] = bq.w;
    }
    float pv[16];
#pragma unroll
    for (int j = 0; j < 8; ++j) {
        int e0 = 2 * j, e1 = 2 * j + 1;
        pv[e0] = fmaxf((acc[e0] + sdec[e0]) * di + bb[e0], 0.f) + bf2f((ushort)(urw[j] & 0xffff));
        pv[e1] = fmaxf((acc[e1] + sdec[e1]) * di + bb[e1], 0.f) + bf2f((ushort)(urw[j] >> 16));
    }
    if (valid) {
#pragma unroll
        for (int e = 0; e < 16; ++e) atomicAdd(&lpool[c0 + e], pv[e]);
    }
    __syncthreads();
    if (t < 128) atomicAdd(&pooled[t], lpool[t]);
}

// ---------------- final: sigmoid(mean @ Wfc + bfc) ----------------

__global__ void k_final(const float* __restrict__ pooled, const float* __restrict__ Wfc,
                        const float* __restrict__ bfc, float* __restrict__ out, float invN) {
    int lane = threadIdx.x;
    float s = pooled[2 * lane] * invN * Wfc[2 * lane] +
              pooled[2 * lane + 1] * invN * Wfc[2 * lane + 1];
#pragma unroll
    for (int off = 32; off > 0; off >>= 1) s += __shfl_down(s, off);
    if (lane == 0) out[0] = 1.f / (1.f + expf(-(s + bfc[0])));
}

// ---------------- launch ----------------

extern "C" void kernel_launch(void* const* d_in, const int* in_sizes, int n_in,
                              void* d_out, int out_size, void* d_ws, size_t ws_size,
                              hipStream_t stream) {
    const float* x   = (const float*)d_in[0];
    const int*   ei  = (const int*)d_in[1];
    const float* W1  = (const float*)d_in[2];
    const float* b1  = (const float*)d_in[3];
    const float* W2  = (const float*)d_in[4];
    const float* b2  = (const float*)d_in[5];
    const float* We  = (const float*)d_in[6];
    const float* be  = (const float*)d_in[7];
    const float* Wfc = (const float*)d_in[8];
    const float* bfc = (const float*)d_in[9];
    float* out = (float*)d_out;

    const int N = in_sizes[0] / 128;
    const int E = in_sizes[1] / 2;
    const int* src = ei;
    const int* dst = ei + E;

    char* w = (char*)d_ws;
    size_t off = 0;
    auto take = [&](size_t bytes) -> void* {
        void* p = w + off;
        off = (off + bytes + 255) & ~(size_t)255;
        return p;
    };
    int*    deg    = (int*)take((size_t)N * 4);
    int*    offs   = (int*)take((size_t)N * 4);
    int*    cursor = (int*)take((size_t)N * 4);
    float*  dinv   = (float*)take((size_t)N * 4);
    int*    bsum   = (int*)take(1024);
    int*    boff   = (int*)take(1024);
    int*    csr    = (int*)take((size_t)(E + 8) * 4);
    uchar*  h1q    = (uchar*)take((size_t)(N + 1) * 128);      // row N = zeros
    ushort* xfc    = (ushort*)take((size_t)N * 128 * 2);
    ushort* h      = (ushort*)take((size_t)N * 128 * 2);
    uchar*  h2q    = (uchar*)take((size_t)(N + 1) * 128);      // row N = zeros
    float*  pooled = (float*)take(512);

    const int nbE = (E + 255) / 256;
    const int nbScan = (N + 1023) / 1024;

    hipMemsetAsync(deg, 0, (size_t)N * 4, stream);
    hipMemsetAsync(cursor, 0, (size_t)N * 4, stream);
    hipMemsetAsync(pooled, 0, 512, stream);
    hipMemsetAsync(h1q + (size_t)N * 128, 0, 128, stream);
    hipMemsetAsync(h2q + (size_t)N * 128, 0, 128, stream);

    k_degree<<<nbE, 256, 0, stream>>>(dst, deg, E);
    k_dinv<<<(N + 255) / 256, 256, 0, stream>>>(deg, dinv, N);
    k_scan_a<<<nbScan, 256, 0, stream>>>(deg, bsum, N);
    k_scan_b<<<1, 256, 0, stream>>>(bsum, boff, nbScan);
    k_scan_c<<<nbScan, 256, 0, stream>>>(deg, boff, offs, N);
    k_fill<<<nbE, 256, 0, stream>>>(src, dst, offs, cursor, csr, E);

    k_gemm1<<<(N + 127) / 128, 512, 0, stream>>>(x, W1, We, be, dinv, h1q, xfc, N);
    k_agg1<<<(N + 31) / 32, 256, 0, stream>>>(csr, offs, deg, dinv, h1q, xfc, b1, h, N);
    k_gemm2<<<(N + 127) / 128, 512, 0, stream>>>(h, W2, dinv, h2q, N);
    k_agg2<<<(N + 31) / 32, 256, 0, stream>>>(csr, offs, deg, dinv, h2q, h, b2, pooled, N);
    k_final<<<1, 64, 0, stream>>>(pooled, Wfc, bfc, out, 1.0f / (float)N);
}

// Round 6
// 422.673 us; speedup vs baseline: 1.1978x; 1.0454x over previous
//
#include <hip/hip_runtime.h>
#include <hip/hip_bf16.h>

typedef unsigned int uint;
typedef unsigned short ushort;
typedef unsigned char uchar;
typedef __attribute__((ext_vector_type(8))) short short8;
typedef __attribute__((ext_vector_type(4))) float f32x4;

__device__ __forceinline__ float bf2f(ushort u) {
    union { uint i; float f; } v; v.i = ((uint)u) << 16; return v.f;
}
__device__ __forceinline__ ushort f2bf(float f) {
    union { float f; uint i; } v; v.f = f;
    uint x = v.i;
    uint r = (x + 0x7FFFu + ((x >> 16) & 1u)) >> 16;
    return (ushort)r;
}
// fp8 e4m3 encode via HW cvt
__device__ __forceinline__ uchar f2q(float f) {
    return (uchar)(__builtin_amdgcn_cvt_pk_fp8_f32(f, 0.f, 0, false) & 0xFF);
}
// decode 4 fp8 from a word (literal selectors required)
__device__ __forceinline__ void q2f4(uint w, float* o) {
    o[0] = __builtin_amdgcn_cvt_f32_fp8(w, 0);
    o[1] = __builtin_amdgcn_cvt_f32_fp8(w, 1);
    o[2] = __builtin_amdgcn_cvt_f32_fp8(w, 2);
    o[3] = __builtin_amdgcn_cvt_f32_fp8(w, 3);
}

// ---------------- graph prep ----------------
// Binned by dst range (bin = blockIdx & 7 -> round-robin XCD): each 64B line
// of deg/cursor/csr is touched by one XCD only -> no cross-XCD partial-line
// writeback amplification (R5: WRITE_SIZE was 107MB for a 6.4MB array).

__global__ void k_degree(const int* __restrict__ dst, int* __restrict__ deg,
                         int e, int n) {
    int bin = blockIdx.x & 7;
    int sub = blockIdx.x >> 3;
    int nsub = gridDim.x >> 3;
    int q = (n + 7) >> 3;
    int lo = bin * q, hi = min(n, lo + q);
    for (int i = sub * 256 + threadIdx.x; i < e; i += nsub * 256) {
        int d = dst[i];
        if (d >= lo && d < hi) atomicAdd(&deg[d], 1);
    }
}

__global__ void k_dinv(const int* __restrict__ deg, float* __restrict__ dinv, int n) {
    int i = blockIdx.x * 256 + threadIdx.x;
    if (i < n) dinv[i] = rsqrtf((float)deg[i] + 1.0f);  // +1 self-loop
}

// 3-kernel exclusive scan of edge-degree -> offsets. chunk = 1024/block.
__global__ void k_scan_a(const int* __restrict__ deg, int* __restrict__ bsum, int n) {
    __shared__ int sd[256];
    int t = threadIdx.x;
    int base = blockIdx.x * 1024 + t * 4;
    int s = 0;
#pragma unroll
    for (int j = 0; j < 4; ++j) { int idx = base + j; if (idx < n) s += deg[idx]; }
    sd[t] = s; __syncthreads();
    for (int off = 1; off < 256; off <<= 1) {
        int v = (t >= off) ? sd[t - off] : 0;
        __syncthreads();
        sd[t] += v;
        __syncthreads();
    }
    if (t == 255) bsum[blockIdx.x] = sd[255];
}

__global__ void k_scan_b(const int* __restrict__ bsum, int* __restrict__ boff, int nb) {
    __shared__ int sd[256];
    int t = threadIdx.x;
    int v0 = (t < nb) ? bsum[t] : 0;
    sd[t] = v0; __syncthreads();
    for (int off = 1; off < 256; off <<= 1) {
        int v = (t >= off) ? sd[t - off] : 0;
        __syncthreads();
        sd[t] += v;
        __syncthreads();
    }
    if (t < nb) boff[t] = sd[t] - v0;  // exclusive
}

__global__ void k_scan_c(const int* __restrict__ deg, const int* __restrict__ boff,
                         int* __restrict__ offs, int n) {
    __shared__ int sd[256];
    int t = threadIdx.x;
    int base = blockIdx.x * 1024 + t * 4;
    int vals[4]; int s = 0;
#pragma unroll
    for (int j = 0; j < 4; ++j) {
        int idx = base + j;
        vals[j] = (idx < n) ? deg[idx] : 0;
        s += vals[j];
    }
    sd[t] = s; __syncthreads();
    for (int off = 1; off < 256; off <<= 1) {
        int v = (t >= off) ? sd[t - off] : 0;
        __syncthreads();
        sd[t] += v;
        __syncthreads();
    }
    int run = boff[blockIdx.x] + (sd[t] - s);
#pragma unroll
    for (int j = 0; j < 4; ++j) {
        int idx = base + j;
        if (idx < n) { offs[idx] = run; run += vals[j]; }
    }
}

__global__ void k_fill(const int* __restrict__ src, const int* __restrict__ dst,
                       const int* __restrict__ offs, int* __restrict__ cursor,
                       int* __restrict__ csr, int e, int n) {
    int bin = blockIdx.x & 7;
    int sub = blockIdx.x >> 3;
    int nsub = gridDim.x >> 3;
    int q = (n + 7) >> 3;
    int lo = bin * q, hi = min(n, lo + q);
    for (int i = sub * 256 + threadIdx.x; i < e; i += nsub * 256) {
        int d = dst[i];
        if (d >= lo && d < hi) {
            int p = offs[d] + atomicAdd(&cursor[d], 1);
            csr[p] = src[i];
        }
    }
}

// ---------------- GEMM1: h1q = fp8((x@W1)*dinv), xfc = bf16(relu(x@We+be)) ----------------

__global__ __launch_bounds__(512) void k_gemm1(
    const float* __restrict__ x, const float* __restrict__ W1, const float* __restrict__ We,
    const float* __restrict__ be, const float* __restrict__ dinv,
    uchar* __restrict__ h1q, ushort* __restrict__ xfc, int n)
{
    __shared__ __align__(16) ushort Bt[256][72];  // [col][k_local], pad 72 for banks
    int tid = threadIdx.x;
    int w = tid >> 6, lane = tid & 63;
    int ln15 = lane & 15, g = lane >> 4;
    int rowBase = blockIdx.x * 128 + w * 16;
    int r = rowBase + ln15;
    bool valid = r < n;

    short8 a[4];
#pragma unroll
    for (int ks = 0; ks < 4; ++ks) {
        float4 f0 = make_float4(0.f, 0.f, 0.f, 0.f), f1 = f0;
        if (valid) {
            const float* p = x + (size_t)r * 128 + ks * 32 + g * 8;
            f0 = *reinterpret_cast<const float4*>(p);
            f1 = *reinterpret_cast<const float4*>(p + 4);
        }
        short8 v;
        v[0] = (short)f2bf(f0.x); v[1] = (short)f2bf(f0.y);
        v[2] = (short)f2bf(f0.z); v[3] = (short)f2bf(f0.w);
        v[4] = (short)f2bf(f1.x); v[5] = (short)f2bf(f1.y);
        v[6] = (short)f2bf(f1.z); v[7] = (short)f2bf(f1.w);
        a[ks] = v;
    }

    f32x4 acc[16];
#pragma unroll
    for (int i = 0; i < 16; ++i) acc[i] = (f32x4){0.f, 0.f, 0.f, 0.f};

    for (int s = 0; s < 2; ++s) {
        for (int i = tid; i < 8192; i += 512) {
            int kl = i >> 7, j = i & 127;
            int kg = s * 64 + kl;
            Bt[j][kl]       = f2bf(W1[kg * 128 + j]);
            Bt[128 + j][kl] = f2bf(We[kg * 128 + j]);
        }
        __syncthreads();
#pragma unroll
        for (int t2 = 0; t2 < 2; ++t2) {
            short8 af = a[s * 2 + t2];
#pragma unroll
            for (int jf = 0; jf < 16; ++jf) {
                short8 bf = *reinterpret_cast<const short8*>(&Bt[jf * 16 + ln15][t2 * 32 + g * 8]);
                acc[jf] = __builtin_amdgcn_mfma_f32_16x16x32_bf16(af, bf, acc[jf], 0, 0, 0);
            }
        }
        __syncthreads();
    }

    float dv[4];
#pragma unroll
    for (int q = 0; q < 4; ++q) {
        int rr = rowBase + g * 4 + q;
        dv[q] = (rr < n) ? dinv[rr] : 0.f;
    }

    // D layout: col = lane&15, row = (lane>>4)*4 + q
#pragma unroll
    for (int jf = 0; jf < 16; ++jf) {
        int col = jf * 16 + ln15;
#pragma unroll
        for (int q = 0; q < 4; ++q) {
            int rr = rowBase + g * 4 + q;
            if (rr < n) {
                float v = acc[jf][q];
                if (col < 128) {
                    h1q[(size_t)rr * 128 + col] = f2q(v * dv[q]);
                } else {
                    float vv = fmaxf(v + be[col - 128], 0.f);
                    xfc[(size_t)rr * 128 + (col - 128)] = f2bf(vv);
                }
            }
        }
    }
}

// ---------------- GEMM2: h2q = fp8((h@W2)*dinv) (bf16 in) ----------------

__global__ __launch_bounds__(512) void k_gemm2(
    const ushort* __restrict__ h, const float* __restrict__ W2, const float* __restrict__ dinv,
    uchar* __restrict__ h2q, int n)
{
    __shared__ __align__(16) ushort Bt[128][72];
    int tid = threadIdx.x;
    int w = tid >> 6, lane = tid & 63;
    int ln15 = lane & 15, g = lane >> 4;
    int rowBase = blockIdx.x * 128 + w * 16;
    int r = rowBase + ln15;
    bool valid = r < n;

    short8 a[4];
#pragma unroll
    for (int ks = 0; ks < 4; ++ks) {
        short8 v = (short8){0,0,0,0,0,0,0,0};
        if (valid) v = *reinterpret_cast<const short8*>(h + (size_t)r * 128 + ks * 32 + g * 8);
        a[ks] = v;
    }

    f32x4 acc[8];
#pragma unroll
    for (int i = 0; i < 8; ++i) acc[i] = (f32x4){0.f, 0.f, 0.f, 0.f};

    for (int s = 0; s < 2; ++s) {
        for (int i = tid; i < 8192; i += 512) {
            int kl = i >> 7, j = i & 127;
            Bt[j][kl] = f2bf(W2[(s * 64 + kl) * 128 + j]);
        }
        __syncthreads();
#pragma unroll
        for (int t2 = 0; t2 < 2; ++t2) {
            short8 af = a[s * 2 + t2];
#pragma unroll
            for (int jf = 0; jf < 8; ++jf) {
                short8 bf = *reinterpret_cast<const short8*>(&Bt[jf * 16 + ln15][t2 * 32 + g * 8]);
                acc[jf] = __builtin_amdgcn_mfma_f32_16x16x32_bf16(af, bf, acc[jf], 0, 0, 0);
            }
        }
        __syncthreads();
    }

    float dv[4];
#pragma unroll
    for (int q = 0; q < 4; ++q) {
        int rr = rowBase + g * 4 + q;
        dv[q] = (rr < n) ? dinv[rr] : 0.f;
    }

#pragma unroll
    for (int jf = 0; jf < 8; ++jf) {
        int col = jf * 16 + ln15;
#pragma unroll
        for (int q = 0; q < 4; ++q) {
            int rr = rowBase + g * 4 + q;
            if (rr < n) h2q[(size_t)rr * 128 + col] = f2q(acc[jf][q] * dv[q]);
        }
    }
}

// ---------------- aggregation 1 ----------------
// h_i = relu(dinv_i*(sum_{s in N(i)} h1q[s] + h1q[i]) + b1) + xfc_i   (bf16 out)
// 8-lane group per node; lane owns 16 channels (16B fp8 gathers).
// Software pipeline: load batch k+1's csr indices while batch k's 8 gathers
// are in flight. csr padded +64 so speculative idx loads stay in-bounds.

__global__ __launch_bounds__(256) void k_agg1(
    const int* __restrict__ csr, const int* __restrict__ offs, const int* __restrict__ degE,
    const float* __restrict__ dinv, const uchar* __restrict__ h1q, const ushort* __restrict__ xfc,
    const float* __restrict__ b1, ushort* __restrict__ h, int n)
{
    int t = threadIdx.x;
    int g = t >> 3, li = t & 7;
    int node = blockIdx.x * 32 + g;
    if (node >= n) return;
    int off = offs[node], cnt = degE[node];
    float di = dinv[node];
    int c0 = li * 16;
    float acc[16];
#pragma unroll
    for (int e = 0; e < 16; ++e) acc[e] = 0.f;

    int nbat = (cnt + 7) >> 3;
    int idx[8];
#pragma unroll
    for (int q = 0; q < 8; ++q) {
        int s = csr[off + q];
        idx[q] = (q < cnt) ? s : n;
    }
    for (int b = 0; b < nbat; ++b) {
        uint4 u[8];
#pragma unroll
        for (int q = 0; q < 8; ++q)
            u[q] = *reinterpret_cast<const uint4*>(h1q + (size_t)idx[q] * 128 + c0);
        // prefetch next batch's indices (overlaps with gathers in flight)
        int base2 = (b + 1) * 8;
        int idxn[8];
#pragma unroll
        for (int q = 0; q < 8; ++q) {
            int s = csr[off + base2 + q];
            idxn[q] = (base2 + q < cnt) ? s : n;
        }
#pragma unroll
        for (int q = 0; q < 8; ++q) {
            const uint* uw = reinterpret_cast<const uint*>(&u[q]);
#pragma unroll
            for (int p = 0; p < 4; ++p) {
                float d4[4]; q2f4(uw[p], d4);
                acc[4 * p + 0] += d4[0];
                acc[4 * p + 1] += d4[1];
                acc[4 * p + 2] += d4[2];
                acc[4 * p + 3] += d4[3];
            }
        }
#pragma unroll
        for (int q = 0; q < 8; ++q) idx[q] = idxn[q];
    }

    uint4 us = *reinterpret_cast<const uint4*>(h1q + (size_t)node * 128 + c0);
    const uint* usw = reinterpret_cast<const uint*>(&us);
    float sdec[16];
#pragma unroll
    for (int p = 0; p < 4; ++p) q2f4(usw[p], &sdec[4 * p]);
    uint4 ux0 = *reinterpret_cast<const uint4*>(xfc + (size_t)node * 128 + c0);
    uint4 ux1 = *reinterpret_cast<const uint4*>(xfc + (size_t)node * 128 + c0 + 8);
    uint uxw[8] = {ux0.x, ux0.y, ux0.z, ux0.w, ux1.x, ux1.y, ux1.z, ux1.w};
    float bb[16];
#pragma unroll
    for (int p = 0; p < 4; ++p) {
        float4 bq = *reinterpret_cast<const float4*>(b1 + c0 + p * 4);
        bb[4 * p] = bq.x; bb[4 * p + 1] = bq.y; bb[4 * p + 2] = bq.z; bb[4 * p + 3] = bq.w;
    }
    uint outw[8];
#pragma unroll
    for (int j = 0; j < 8; ++j) {
        int e0 = 2 * j, e1 = 2 * j + 1;
        float v0 = fmaxf((acc[e0] + sdec[e0]) * di + bb[e0], 0.f) + bf2f((ushort)(uxw[j] & 0xffff));
        float v1 = fmaxf((acc[e1] + sdec[e1]) * di + bb[e1], 0.f) + bf2f((ushort)(uxw[j] >> 16));
        outw[j] = (uint)f2bf(v0) | ((uint)f2bf(v1) << 16);
    }
    ushort* hp = h + (size_t)node * 128 + c0;
    *reinterpret_cast<uint4*>(hp)     = make_uint4(outw[0], outw[1], outw[2], outw[3]);
    *reinterpret_cast<uint4*>(hp + 8) = make_uint4(outw[4], outw[5], outw[6], outw[7]);
}

// ---------------- aggregation 2 + residual + pool (no per-node output) ----------------
// pool_c += relu(dinv_i*(sum h2q[s] + h2q[i]) + b2)_c + h_i_c

__global__ __launch_bounds__(256) void k_agg2(
    const int* __restrict__ csr, const int* __restrict__ offs, const int* __restrict__ degE,
    const float* __restrict__ dinv, const uchar* __restrict__ h2q, const ushort* __restrict__ hres,
    const float* __restrict__ b2, float* __restrict__ pooled, int n)
{
    __shared__ float lpool[128];
    int t = threadIdx.x;
    if (t < 128) lpool[t] = 0.f;
    __syncthreads();
    int g = t >> 3, li = t & 7;
    int node = blockIdx.x * 32 + g;
    bool valid = node < n;
    int nodeC = valid ? node : (n - 1);
    int off = offs[nodeC];
    int cnt = valid ? degE[nodeC] : 0;
    float di = dinv[nodeC];
    int c0 = li * 16;
    float acc[16];
#pragma unroll
    for (int e = 0; e < 16; ++e) acc[e] = 0.f;

    int nbat = (cnt + 7) >> 3;
    int idx[8];
#pragma unroll
    for (int q = 0; q < 8; ++q) {
        int s = csr[off + q];
        idx[q] = (q < cnt) ? s : n;
    }
    for (int b = 0; b < nbat; ++b) {
        uint4 u[8];
#pragma unroll
        for (int q = 0; q < 8; ++q)
            u[q] = *reinterpret_cast<const uint4*>(h2q + (size_t)idx[q] * 128 + c0);
        int base2 = (b + 1) * 8;
        int idxn[8];
#pragma unroll
        for (int q = 0; q < 8; ++q) {
            int s = csr[off + base2 + q];
            idxn[q] = (base2 + q < cnt) ? s : n;
        }
#pragma unroll
        for (int q = 0; q < 8; ++q) {
            const uint* uw = reinterpret_cast<const uint*>(&u[q]);
#pragma unroll
            for (int p = 0; p < 4; ++p) {
                float d4[4]; q2f4(uw[p], d4);
                acc[4 * p + 0] += d4[0];
                acc[4 * p + 1] += d4[1];
                acc[4 * p + 2] += d4[2];
                acc[4 * p + 3] += d4[3];
            }
        }
#pragma unroll
        for (int q = 0; q < 8; ++q) idx[q] = idxn[q];
    }

    uint4 us = *reinterpret_cast<const uint4*>(h2q + (size_t)nodeC * 128 + c0);
    const uint* usw = reinterpret_cast<const uint*>(&us);
    float sdec[16];
#pragma unroll
    for (int p = 0; p < 4; ++p) q2f4(usw[p], &sdec[4 * p]);
    uint4 ur0 = *reinterpret_cast<const uint4*>(hres + (size_t)nodeC * 128 + c0);
    uint4 ur1 = *reinterpret_cast<const uint4*>(hres + (size_t)nodeC * 128 + c0 + 8);
    uint urw[8] = {ur0.x, ur0.y, ur0.z, ur0.w, ur1.x, ur1.y, ur1.z, ur1.w};
    float bb[16];
#pragma unroll
    for (int p = 0; p < 4; ++p) {
        float4 bq = *reinterpret_cast<const float4*>(b2 + c0 + p * 4);
        bb[4 * p] = bq.x; bb[4 * p + 1] = bq.y; bb[4 * p + 2] = bq.z; bb[4 * p + 3] = bq.w;
    }
    float pv[16];
#pragma unroll
    for (int j = 0; j < 8; ++j) {
        int e0 = 2 * j, e1 = 2 * j + 1;
        pv[e0] = fmaxf((acc[e0] + sdec[e0]) * di + bb[e0], 0.f) + bf2f((ushort)(urw[j] & 0xffff));
        pv[e1] = fmaxf((acc[e1] + sdec[e1]) * di + bb[e1], 0.f) + bf2f((ushort)(urw[j] >> 16));
    }
    if (valid) {
#pragma unroll
        for (int e = 0; e < 16; ++e) atomicAdd(&lpool[c0 + e], pv[e]);
    }
    __syncthreads();
    if (t < 128) atomicAdd(&pooled[t], lpool[t]);
}

// ---------------- final: sigmoid(mean @ Wfc + bfc) ----------------

__global__ void k_final(const float* __restrict__ pooled, const float* __restrict__ Wfc,
                        const float* __restrict__ bfc, float* __restrict__ out, float invN) {
    int lane = threadIdx.x;
    float s = pooled[2 * lane] * invN * Wfc[2 * lane] +
              pooled[2 * lane + 1] * invN * Wfc[2 * lane + 1];
#pragma unroll
    for (int off = 32; off > 0; off >>= 1) s += __shfl_down(s, off);
    if (lane == 0) out[0] = 1.f / (1.f + expf(-(s + bfc[0])));
}

// ---------------- launch ----------------

extern "C" void kernel_launch(void* const* d_in, const int* in_sizes, int n_in,
                              void* d_out, int out_size, void* d_ws, size_t ws_size,
                              hipStream_t stream) {
    const float* x   = (const float*)d_in[0];
    const int*   ei  = (const int*)d_in[1];
    const float* W1  = (const float*)d_in[2];
    const float* b1  = (const float*)d_in[3];
    const float* W2  = (const float*)d_in[4];
    const float* b2  = (const float*)d_in[5];
    const float* We  = (const float*)d_in[6];
    const float* be  = (const float*)d_in[7];
    const float* Wfc = (const float*)d_in[8];
    const float* bfc = (const float*)d_in[9];
    float* out = (float*)d_out;

    const int N = in_sizes[0] / 128;
    const int E = in_sizes[1] / 2;
    const int* src = ei;
    const int* dst = ei + E;

    char* w = (char*)d_ws;
    size_t off = 0;
    auto take = [&](size_t bytes) -> void* {
        void* p = w + off;
        off = (off + bytes + 255) & ~(size_t)255;
        return p;
    };
    int*    deg    = (int*)take((size_t)N * 4);
    int*    offs   = (int*)take((size_t)N * 4);
    int*    cursor = (int*)take((size_t)N * 4);
    float*  dinv   = (float*)take((size_t)N * 4);
    int*    bsum   = (int*)take(1024);
    int*    boff   = (int*)take(1024);
    int*    csr    = (int*)take((size_t)(E + 64) * 4);
    uchar*  h1q    = (uchar*)take((size_t)(N + 1) * 128);      // row N = zeros
    ushort* xfc    = (ushort*)take((size_t)N * 128 * 2);
    ushort* h      = (ushort*)take((size_t)N * 128 * 2);
    uchar*  h2q    = (uchar*)take((size_t)(N + 1) * 128);      // row N = zeros
    float*  pooled = (float*)take(512);

    const int nbScan = (N + 1023) / 1024;

    hipMemsetAsync(deg, 0, (size_t)N * 4, stream);
    hipMemsetAsync(cursor, 0, (size_t)N * 4, stream);
    hipMemsetAsync(pooled, 0, 512, stream);
    hipMemsetAsync(h1q + (size_t)N * 128, 0, 128, stream);
    hipMemsetAsync(h2q + (size_t)N * 128, 0, 128, stream);

    k_degree<<<2048, 256, 0, stream>>>(dst, deg, E, N);
    k_dinv<<<(N + 255) / 256, 256, 0, stream>>>(deg, dinv, N);
    k_scan_a<<<nbScan, 256, 0, stream>>>(deg, bsum, N);
    k_scan_b<<<1, 256, 0, stream>>>(bsum, boff, nbScan);
    k_scan_c<<<nbScan, 256, 0, stream>>>(deg, boff, offs, N);
    k_fill<<<2048, 256, 0, stream>>>(src, dst, offs, cursor, csr, E, N);

    k_gemm1<<<(N + 127) / 128, 512, 0, stream>>>(x, W1, We, be, dinv, h1q, xfc, N);
    k_agg1<<<(N + 31) / 32, 256, 0, stream>>>(csr, offs, deg, dinv, h1q, xfc, b1, h, N);
    k_gemm2<<<(N + 127) / 128, 512, 0, stream>>>(h, W2, dinv, h2q, N);
    k_agg2<<<(N + 31) / 32, 256, 0, stream>>>(csr, offs, deg, dinv, h2q, h, b2, pooled, N);
    k_final<<<1, 64, 0, stream>>>(pooled, Wfc, bfc, out, 1.0f / (float)N);
}